// Round 1
// baseline (118.009 us; speedup 1.0000x reference)
//
#include <hip/hip_runtime.h>
#include <math.h>

// LDS strides (floats). All chosen so row stride % 32 == 4 (bank spread)
// and stride*4 % 16 == 0 (float4-aligned rows).
constexpr int SV  = 100;  // V  [64][96]  padded
constexpr int SC  = 132;  // C  [64][128] padded
constexpr int SH1 = 68;   // H1 [64][64]  padded
constexpr int SH2 = 36;   // H2 [64][32]  padded
constexpr int SH3 = 20;   // H3 [64][16]  padded

__global__ __launch_bounds__(256, 2)
void flatnet_fused(const float* __restrict__ pgi,
                   const float* __restrict__ Wl, const float* __restrict__ bl,
                   const float* __restrict__ Wc, const float* __restrict__ bc,
                   const float* __restrict__ W1, const float* __restrict__ b1,
                   const float* __restrict__ W2, const float* __restrict__ b2,
                   const float* __restrict__ W3, const float* __restrict__ b3,
                   const float* __restrict__ W4, const float* __restrict__ b4,
                   float* __restrict__ out)
{
    __shared__ float sA[64 * SV];   // V -> H1 -> H3
    __shared__ float sB[64 * SC];   // C -> H2

    const int t   = threadIdx.x;
    const int blk = blockIdx.x;

    // ================= Phase 0: lift (3->32, leaky 0.2) + ring-group max =================
    {
        const int ln = t >> 2;          // local node 0..63
        const int q  = t & 3;           // this thread handles dims q*8 .. q*8+7
        const int gn = blk * 64 + ln;   // global node = b*1024 + gi*32 + gj
        const int b  = gn >> 10;
        const int g  = gn & 1023;
        const int gi = g >> 5, gj = g & 31;

        float w0[8], w1[8], w2[8], bb[8];
        #pragma unroll
        for (int d = 0; d < 8; ++d) {
            const int dd = q * 8 + d;
            w0[d] = Wl[dd];         // Wl[0][dd]
            w1[d] = Wl[32 + dd];    // Wl[1][dd]
            w2[d] = Wl[64 + dd];    // Wl[2][dd]
            bb[d] = bl[dd];
        }

        float gm[3][8];
        #pragma unroll
        for (int gg = 0; gg < 3; ++gg)
            #pragma unroll
            for (int d = 0; d < 8; ++d) gm[gg][d] = -INFINITY;

        // ring group of each (pi,pj): d8=min(pi,pj,7-pi,7-pj); 0=inner(d8==3),1=inter(d8==2),2=outer
        constexpr int GT[8][8] = {
            {2,2,2,2,2,2,2,2},
            {2,2,2,2,2,2,2,2},
            {2,2,1,1,1,1,2,2},
            {2,2,1,0,0,1,2,2},
            {2,2,1,0,0,1,2,2},
            {2,2,1,1,1,1,2,2},
            {2,2,2,2,2,2,2,2},
            {2,2,2,2,2,2,2,2},
        };

        const size_t rowbase = (size_t)b * 65536 + ((size_t)gi * 8) * 256 + (size_t)gj * 8;
        #pragma unroll
        for (int pi = 0; pi < 8; ++pi) {
            // 8 points of this patch row = 24 contiguous floats, 96B-aligned -> 6x float4
            const float4* src = (const float4*)(pgi + (rowbase + (size_t)pi * 256) * 3);
            float f[24];
            #pragma unroll
            for (int l = 0; l < 6; ++l) {
                const float4 v = src[l];
                f[l*4+0] = v.x; f[l*4+1] = v.y; f[l*4+2] = v.z; f[l*4+3] = v.w;
            }
            #pragma unroll
            for (int pj = 0; pj < 8; ++pj) {
                const int grp = GT[pi][pj];
                const float x = f[pj*3], y = f[pj*3+1], z = f[pj*3+2];
                #pragma unroll
                for (int d = 0; d < 8; ++d) {
                    float v = fmaf(x, w0[d], bb[d]);
                    v = fmaf(y, w1[d], v);
                    v = fmaf(z, w2[d], v);
                    v = fmaxf(v, 0.2f * v);              // leaky_relu 0.2
                    gm[grp][d] = fmaxf(gm[grp][d], v);
                }
            }
        }
        // V row layout: [inner(0..31) | inter(32..63) | outer(64..95)]
        #pragma unroll
        for (int gg = 0; gg < 3; ++gg) {
            float4 lo = make_float4(gm[gg][0], gm[gg][1], gm[gg][2], gm[gg][3]);
            float4 hi = make_float4(gm[gg][4], gm[gg][5], gm[gg][6], gm[gg][7]);
            *(float4*)&sA[ln*SV + gg*32 + q*8]     = lo;
            *(float4*)&sA[ln*SV + gg*32 + q*8 + 4] = hi;
        }
    }
    __syncthreads();

    // ================= Phase 1: C = leaky(V[64,96] @ Wc[96,128] + bc) =================
    {
        const int ri = t >> 5;        // 0..7  -> rows ri*8 .. +7
        const int c0 = (t & 31) * 4;  // cols c0..c0+3
        float acc[8][4];
        {
            const float4 bv = *(const float4*)&bc[c0];
            #pragma unroll
            for (int r = 0; r < 8; ++r) { acc[r][0]=bv.x; acc[r][1]=bv.y; acc[r][2]=bv.z; acc[r][3]=bv.w; }
        }
        for (int j = 0; j < 96; j += 4) {
            float4 a[8];
            #pragma unroll
            for (int r = 0; r < 8; ++r) a[r] = *(const float4*)&sA[(ri*8+r)*SV + j];
            #pragma unroll
            for (int jj = 0; jj < 4; ++jj) {
                const float4 w = *(const float4*)&Wc[(j+jj)*128 + c0];
                #pragma unroll
                for (int r = 0; r < 8; ++r) {
                    const float av = (jj==0)?a[r].x:(jj==1)?a[r].y:(jj==2)?a[r].z:a[r].w;
                    acc[r][0] = fmaf(av, w.x, acc[r][0]);
                    acc[r][1] = fmaf(av, w.y, acc[r][1]);
                    acc[r][2] = fmaf(av, w.z, acc[r][2]);
                    acc[r][3] = fmaf(av, w.w, acc[r][3]);
                }
            }
        }
        #pragma unroll
        for (int r = 0; r < 8; ++r) {
            float4 o;
            o.x = fmaxf(acc[r][0], 0.2f*acc[r][0]);
            o.y = fmaxf(acc[r][1], 0.2f*acc[r][1]);
            o.z = fmaxf(acc[r][2], 0.2f*acc[r][2]);
            o.w = fmaxf(acc[r][3], 0.2f*acc[r][3]);
            *(float4*)&sB[(ri*8+r)*SC + c0] = o;
        }
    }
    __syncthreads();

    // ================= Phase 2: H1 = relu(C[64,128] @ W1[128,64] + b1) =================
    {
        const int ri = t >> 4;        // 0..15 -> rows ri*4 .. +3
        const int c0 = (t & 15) * 4;
        float acc[4][4];
        {
            const float4 bv = *(const float4*)&b1[c0];
            #pragma unroll
            for (int r = 0; r < 4; ++r) { acc[r][0]=bv.x; acc[r][1]=bv.y; acc[r][2]=bv.z; acc[r][3]=bv.w; }
        }
        for (int j = 0; j < 128; j += 4) {
            float4 a[4];
            #pragma unroll
            for (int r = 0; r < 4; ++r) a[r] = *(const float4*)&sB[(ri*4+r)*SC + j];
            #pragma unroll
            for (int jj = 0; jj < 4; ++jj) {
                const float4 w = *(const float4*)&W1[(j+jj)*64 + c0];
                #pragma unroll
                for (int r = 0; r < 4; ++r) {
                    const float av = (jj==0)?a[r].x:(jj==1)?a[r].y:(jj==2)?a[r].z:a[r].w;
                    acc[r][0] = fmaf(av, w.x, acc[r][0]);
                    acc[r][1] = fmaf(av, w.y, acc[r][1]);
                    acc[r][2] = fmaf(av, w.z, acc[r][2]);
                    acc[r][3] = fmaf(av, w.w, acc[r][3]);
                }
            }
        }
        #pragma unroll
        for (int r = 0; r < 4; ++r) {
            float4 o;
            o.x = fmaxf(acc[r][0], 0.f); o.y = fmaxf(acc[r][1], 0.f);
            o.z = fmaxf(acc[r][2], 0.f); o.w = fmaxf(acc[r][3], 0.f);
            *(float4*)&sA[(ri*4+r)*SH1 + c0] = o;
        }
    }
    __syncthreads();

    // ================= Phase 3: H2 = relu(H1[64,64] @ W2[64,32] + b2) =================
    {
        const int ri = t >> 3;        // 0..31 -> rows ri*2 .. +1
        const int c0 = (t & 7) * 4;
        float acc[2][4];
        {
            const float4 bv = *(const float4*)&b2[c0];
            #pragma unroll
            for (int r = 0; r < 2; ++r) { acc[r][0]=bv.x; acc[r][1]=bv.y; acc[r][2]=bv.z; acc[r][3]=bv.w; }
        }
        for (int j = 0; j < 64; j += 4) {
            float4 a[2];
            #pragma unroll
            for (int r = 0; r < 2; ++r) a[r] = *(const float4*)&sA[(ri*2+r)*SH1 + j];
            #pragma unroll
            for (int jj = 0; jj < 4; ++jj) {
                const float4 w = *(const float4*)&W2[(j+jj)*32 + c0];
                #pragma unroll
                for (int r = 0; r < 2; ++r) {
                    const float av = (jj==0)?a[r].x:(jj==1)?a[r].y:(jj==2)?a[r].z:a[r].w;
                    acc[r][0] = fmaf(av, w.x, acc[r][0]);
                    acc[r][1] = fmaf(av, w.y, acc[r][1]);
                    acc[r][2] = fmaf(av, w.z, acc[r][2]);
                    acc[r][3] = fmaf(av, w.w, acc[r][3]);
                }
            }
        }
        #pragma unroll
        for (int r = 0; r < 2; ++r) {
            float4 o;
            o.x = fmaxf(acc[r][0], 0.f); o.y = fmaxf(acc[r][1], 0.f);
            o.z = fmaxf(acc[r][2], 0.f); o.w = fmaxf(acc[r][3], 0.f);
            *(float4*)&sB[(ri*2+r)*SH2 + c0] = o;
        }
    }
    __syncthreads();

    // ================= Phase 4: H3 = relu(H2[64,32] @ W3[32,16] + b3) =================
    {
        const int row = t >> 2;       // 0..63
        const int c0  = (t & 3) * 4;
        float acc[4];
        {
            const float4 bv = *(const float4*)&b3[c0];
            acc[0]=bv.x; acc[1]=bv.y; acc[2]=bv.z; acc[3]=bv.w;
        }
        for (int j = 0; j < 32; j += 4) {
            const float4 a = *(const float4*)&sB[row*SH2 + j];
            #pragma unroll
            for (int jj = 0; jj < 4; ++jj) {
                const float4 w = *(const float4*)&W3[(j+jj)*16 + c0];
                const float av = (jj==0)?a.x:(jj==1)?a.y:(jj==2)?a.z:a.w;
                acc[0] = fmaf(av, w.x, acc[0]);
                acc[1] = fmaf(av, w.y, acc[1]);
                acc[2] = fmaf(av, w.z, acc[2]);
                acc[3] = fmaf(av, w.w, acc[3]);
            }
        }
        float4 o;
        o.x = fmaxf(acc[0], 0.f); o.y = fmaxf(acc[1], 0.f);
        o.z = fmaxf(acc[2], 0.f); o.w = fmaxf(acc[3], 0.f);
        *(float4*)&sA[row*SH3 + c0] = o;
    }
    __syncthreads();

    // ================= Phase 5: out = H3[64,16] @ W4[16,3] + b4 =================
    if (t < 64) {
        float acc0 = b4[0], acc1 = b4[1], acc2 = b4[2];
        float a[16];
        #pragma unroll
        for (int l = 0; l < 4; ++l) {
            const float4 v = *(const float4*)&sA[t*SH3 + l*4];
            a[l*4+0]=v.x; a[l*4+1]=v.y; a[l*4+2]=v.z; a[l*4+3]=v.w;
        }
        #pragma unroll
        for (int j = 0; j < 16; ++j) {
            acc0 = fmaf(a[j], W4[j*3+0], acc0);   // uniform addr -> scalar loads
            acc1 = fmaf(a[j], W4[j*3+1], acc1);
            acc2 = fmaf(a[j], W4[j*3+2], acc2);
        }
        const size_t gn = (size_t)blk * 64 + t;
        out[gn*3 + 0] = acc0;
        out[gn*3 + 1] = acc1;
        out[gn*3 + 2] = acc2;
    }
}

extern "C" void kernel_launch(void* const* d_in, const int* in_sizes, int n_in,
                              void* d_out, int out_size, void* d_ws, size_t ws_size,
                              hipStream_t stream)
{
    const float* pgi = (const float*)d_in[0];
    const float* Wl  = (const float*)d_in[1];
    const float* bl  = (const float*)d_in[2];
    const float* Wc  = (const float*)d_in[3];
    const float* bc  = (const float*)d_in[4];
    const float* W1  = (const float*)d_in[5];
    const float* b1  = (const float*)d_in[6];
    const float* W2  = (const float*)d_in[7];
    const float* b2  = (const float*)d_in[8];
    const float* W3  = (const float*)d_in[9];
    const float* b3  = (const float*)d_in[10];
    const float* W4  = (const float*)d_in[11];
    const float* b4  = (const float*)d_in[12];

    hipLaunchKernelGGL(flatnet_fused, dim3(512), dim3(256), 0, stream,
                       pgi, Wl, bl, Wc, bc, W1, b1, W2, b2, W3, b3, W4, b4,
                       (float*)d_out);
}